// Round 6
// baseline (115.988 us; speedup 1.0000x reference)
//
#include <hip/hip_runtime.h>
#include <hip/hip_bf16.h>
#include <cstdint>

#define N_PTS 8192
#define DIM 128
#define NT 128                    // 8192/64 row-tiles
#define NBLK (NT * (NT + 1) / 2)  // 8256 upper-triangle 64x64 tiles

// Base-2-domain circle-loss constants (gamma=256, m=0.25, folded log2(e)).
// lp_nat = (1.25-s)(0.75-s)*256 = 256 s^2 - 512 s + 240   (1.25-s>0 always)
// ln_nat = max(s+0.25,0)*(s-0.25)*256 = (s>-0.25) ? 256 s^2 - 16 : 0
#define KC2 369.3299304675746f    //  256*log2e
#define KC1 -738.6598609351493f   // -512*log2e
#define KC0 346.2468098133512f    //  240*log2e
#define KCN0 -23.083120654223414f // -16*log2e
#define NEGH -1e30f
#define LN2F 0.6931471805599453f

typedef __attribute__((ext_vector_type(8))) __bf16 bf16x8;
typedef __attribute__((ext_vector_type(4))) float f32x4;

// RNE float -> bf16 bits (inputs are finite, no NaN handling needed)
__device__ __forceinline__ unsigned short f2bf(float x) {
  unsigned int u = __float_as_uint(x);
  unsigned int r = (u + 0x7FFFu + ((u >> 16) & 1u)) >> 16;
  return (unsigned short)r;
}

// 32 lanes per row (float4/lane), 8 rows per block: L2-normalize, store bf16.
// Also: pack labels to u8.
__global__ __launch_bounds__(256) void normalize_kernel(const float* __restrict__ feat,
                                                        const int* __restrict__ labels,
                                                        unsigned short* __restrict__ fb,
                                                        unsigned char* __restrict__ lab8) {
  const int gid = blockIdx.x * 256 + threadIdx.x;
  if (gid < N_PTS) lab8[gid] = (unsigned char)labels[gid];
  const int row = blockIdx.x * 8 + (threadIdx.x >> 5);
  const int l32 = threadIdx.x & 31;
  const float4 v = *(const float4*)(feat + row * DIM + l32 * 4);
  float ss = v.x * v.x + v.y * v.y + v.z * v.z + v.w * v.w;
#pragma unroll
  for (int o = 16; o > 0; o >>= 1) ss += __shfl_xor(ss, o);  // stays in 32-group
  const float inv = 1.0f / fmaxf(sqrtf(ss), 1e-12f);
  uint2 pack;
  pack.x = (unsigned int)f2bf(v.x * inv) | ((unsigned int)f2bf(v.y * inv) << 16);
  pack.y = (unsigned int)f2bf(v.z * inv) | ((unsigned int)f2bf(v.w * inv) << 16);
  *(uint2*)(fb + row * DIM + l32 * 4) = pack;
}

// Wave-independent 64x64 tiles: ZERO LDS, ZERO barriers. Each wave gathers its
// MFMA fragments DIRECTLY from global (L2-resident fb): for fragment x, lanes
// (rsel=lane&15, kgrp=lane>>4) read 16 rows x 64B, each 64B line covered by
// exactly 4 lanes -> fully coalesced. K-loop uses a 2-deep register double-
// buffer so step k+2's loads hide under step k's MFMAs. Rationale (round-5
// post-mortem): occupancy is VGPR-capped at 4 waves/SIMD (64-reg accumulator
// => >112 VGPR always), so barrier convoys + LDS staging were the stall, and
// staging K=128 L2-resident data through LDS was pure overhead.
__global__ __launch_bounds__(256) void pair_kernel(const unsigned short* __restrict__ f,
                                                   const unsigned char* __restrict__ lab8,
                                                   float4* __restrict__ partials) {
  const int lane = threadIdx.x & 63;
  const int tid = blockIdx.x * 4 + (threadIdx.x >> 6);  // virtual tile id, 0..NBLK-1

  // triangular decode over 128 row-tiles: offset(i) = i*(257-i)/2
  int tI = (int)((257.0f - sqrtf(66049.0f - 8.0f * (float)tid)) * 0.5f);
  while (tI * (257 - tI) / 2 > tid) --tI;
  while ((tI + 1) * (256 - tI) / 2 <= tid) ++tI;
  const int tJ = tI + (tid - tI * (257 - tI) / 2);

  const int rsel = lane & 15, kgrp = lane >> 4;
  const int rowA0 = tI * 64, rowB0 = tJ * 64;

  // per-lane fragment base pointers (16B aligned)
  const unsigned short* pA = f + (size_t)(rowA0 + rsel) * DIM + kgrp * 8;
  const unsigned short* pB = f + (size_t)(rowB0 + rsel) * DIM + kgrp * 8;

  // epilogue label gathers issued early; latency hides under the K-loop
  const int ibase = rowA0 + kgrp * 4;
  const int jbase = rowB0 + rsel;
  unsigned int liPack[4], lj[4];
#pragma unroll
  for (int tn = 0; tn < 4; ++tn) lj[tn] = lab8[jbase + tn * 16];
#pragma unroll
  for (int tm = 0; tm < 4; ++tm)
    liPack[tm] = *(const unsigned int*)(lab8 + ibase + tm * 16);  // 4 labels packed

  f32x4 acc[4][4];
#pragma unroll
  for (int a = 0; a < 4; ++a)
#pragma unroll
    for (int b = 0; b < 4; ++b) acc[a][b] = (f32x4){0.f, 0.f, 0.f, 0.f};

#define LOADF(FA, FB, KK)                                            \
  do {                                                               \
    _Pragma("unroll") for (int x = 0; x < 4; ++x) {                  \
      FA[x] = *(const bf16x8*)(pA + x * 16 * DIM + (KK) * 32);       \
      FB[x] = *(const bf16x8*)(pB + x * 16 * DIM + (KK) * 32);       \
    }                                                                \
  } while (0)
#define MFMA16(FA, FB)                                               \
  do {                                                               \
    _Pragma("unroll") for (int tm = 0; tm < 4; ++tm)                 \
        _Pragma("unroll") for (int tn = 0; tn < 4; ++tn)             \
            acc[tm][tn] = __builtin_amdgcn_mfma_f32_16x16x32_bf16(   \
                FA[tm], FB[tn], acc[tm][tn], 0, 0, 0);               \
  } while (0)

  bf16x8 a0[4], b0[4], a1[4], b1[4];
  LOADF(a0, b0, 0);
  LOADF(a1, b1, 1);   // 2 K-steps in flight
  MFMA16(a0, b0);
  LOADF(a0, b0, 2);   // issued behind step-0 MFMAs, used 2 steps later
  MFMA16(a1, b1);
  LOADF(a1, b1, 3);
  MFMA16(a0, b0);
  MFMA16(a1, b1);
#undef LOADF
#undef MFMA16

  // ---- epilogue: circle-loss logits (base-2 domain) + in-wave logsumexp ----
  // C/D mapping (16x16x32): col = lane&15 (j/B side), row = (lane>>4)*4 + reg

  // pass 1: selected logit in-place, per-thread maxes
  float mp = NEGH, mn = NEGH;
  if (tI != tJ) {  // all 4096 pairs valid (j > i globally)
#pragma unroll
    for (int tm = 0; tm < 4; ++tm)
#pragma unroll
      for (int tn = 0; tn < 4; ++tn)
#pragma unroll
        for (int r = 0; r < 4; ++r) {
          const float s = acc[tm][tn][r];
          const float w = s * KC2;
          const float lp = fmaf(s, w + KC1, KC0);
          const float ln = (s > -0.25f) ? fmaf(s, w, KCN0) : 0.f;
          const bool eq = (((liPack[tm] >> (r * 8)) & 0xFFu) == lj[tn]);
          acc[tm][tn][r] = eq ? lp : ln;
          mp = fmaxf(mp, eq ? lp : NEGH);
          mn = fmaxf(mn, eq ? NEGH : ln);
        }
  } else {  // diagonal tile: mask out j <= i
#pragma unroll
    for (int tm = 0; tm < 4; ++tm)
#pragma unroll
      for (int tn = 0; tn < 4; ++tn) {
        const int d = (jbase + tn * 16) - (ibase + tm * 16);  // valid iff d > r
#pragma unroll
        for (int r = 0; r < 4; ++r) {
          const float s = acc[tm][tn][r];
          const float w = s * KC2;
          const float lp = fmaf(s, w + KC1, KC0);
          const float ln = (s > -0.25f) ? fmaf(s, w, KCN0) : 0.f;
          const bool eq = (((liPack[tm] >> (r * 8)) & 0xFFu) == lj[tn]);
          const bool valid = d > r;
          float u = eq ? lp : ln;
          u = valid ? u : NEGH;
          acc[tm][tn][r] = u;
          mp = fmaxf(mp, (eq && valid) ? lp : NEGH);
          mn = fmaxf(mn, (!eq && valid) ? ln : NEGH);
        }
      }
  }
  // in-wave butterfly: all 64 lanes end with the wave max (no LDS, no barrier)
#pragma unroll
  for (int o = 32; o > 0; o >>= 1) {
    mp = fmaxf(mp, __shfl_xor(mp, o));
    mn = fmaxf(mn, __shfl_xor(mn, o));
  }
  // Clamp keeps exp2(NEGH - M) == 0 even when a stream is empty in this tile.
  const float Mp = fmaxf(mp, -1e28f);
  const float Mn = fmaxf(mn, -1e28f);

  // pass 2: one exp2 per element, route to the owning stream
  float sp = 0.f, sn = 0.f;
#pragma unroll
  for (int tm = 0; tm < 4; ++tm)
#pragma unroll
    for (int tn = 0; tn < 4; ++tn)
#pragma unroll
      for (int r = 0; r < 4; ++r) {
        const bool eq = (((liPack[tm] >> (r * 8)) & 0xFFu) == lj[tn]);
        const float e = __builtin_amdgcn_exp2f(acc[tm][tn][r] - (eq ? Mp : Mn));
        sp += eq ? e : 0.f;
        sn += eq ? 0.f : e;
      }
#pragma unroll
  for (int o = 32; o > 0; o >>= 1) {
    sp += __shfl_xor(sp, o);
    sn += __shfl_xor(sn, o);
  }
  if (lane == 0) partials[tid] = make_float4(Mp, sp, Mn, sn);
}

// Merge 8256 (m2,s2) base-2 partials for both streams; softplus(lse_p + lse_n).
__global__ __launch_bounds__(256) void finalize_kernel(const float4* __restrict__ partials,
                                                       float* __restrict__ out) {
  const int t = threadIdx.x;
  float mp = NEGH, sp = 0.f, mn = NEGH, sn = 0.f;
  for (int i = t; i < NBLK; i += 256) {
    const float4 p = partials[i];
    {
      const float m = fmaxf(mp, p.x);
      sp = sp * __builtin_amdgcn_exp2f(mp - m) + p.y * __builtin_amdgcn_exp2f(p.x - m);
      mp = m;
    }
    {
      const float m = fmaxf(mn, p.z);
      sn = sn * __builtin_amdgcn_exp2f(mn - m) + p.w * __builtin_amdgcn_exp2f(p.z - m);
      mn = m;
    }
  }
  __shared__ float smp[256], ssp[256], smn[256], ssn[256];
  smp[t] = mp; ssp[t] = sp; smn[t] = mn; ssn[t] = sn;
  __syncthreads();
  for (int off = 128; off > 0; off >>= 1) {
    if (t < off) {
      {
        const float m2 = smp[t + off], s2 = ssp[t + off];
        const float m = fmaxf(smp[t], m2);
        ssp[t] = ssp[t] * __builtin_amdgcn_exp2f(smp[t] - m) + s2 * __builtin_amdgcn_exp2f(m2 - m);
        smp[t] = m;
      }
      {
        const float m2 = smn[t + off], s2 = ssn[t + off];
        const float m = fmaxf(smn[t], m2);
        ssn[t] = ssn[t] * __builtin_amdgcn_exp2f(smn[t] - m) + s2 * __builtin_amdgcn_exp2f(m2 - m);
        smn[t] = m;
      }
    }
    __syncthreads();
  }
  if (t == 0) {
    const float lsep = (smp[0] + __builtin_amdgcn_logf(ssp[0])) * LN2F;  // base-2 -> nat
    const float lsen = (smn[0] + __builtin_amdgcn_logf(ssn[0])) * LN2F;
    const float x = lsep + lsen;
    out[0] = fmaxf(x, 0.f) + log1pf(__expf(-fabsf(x)));  // stable softplus
  }
}

extern "C" void kernel_launch(void* const* d_in, const int* in_sizes, int n_in,
                              void* d_out, int out_size, void* d_ws, size_t ws_size,
                              hipStream_t stream) {
  const float* feat = (const float*)d_in[0];
  const int* labels = (const int*)d_in[1];
  float* out = (float*)d_out;

  unsigned short* fb = (unsigned short*)d_ws;                    // 2 MiB
  char* base = (char*)d_ws + (size_t)N_PTS * DIM * 2;
  float4* partials = (float4*)base;                              // 8256*16 = 132 KB
  unsigned char* lab8 = (unsigned char*)(base + NBLK * 16);      // 8192 B

  normalize_kernel<<<N_PTS / 8, 256, 0, stream>>>(feat, labels, fb, lab8);
  pair_kernel<<<NBLK / 4, 256, 0, stream>>>(fb, lab8, partials);
  finalize_kernel<<<1, 256, 0, stream>>>(partials, out);
}